// Round 2
// baseline (72.653 us; speedup 1.0000x reference)
//
#include <hip/hip_runtime.h>
#include <hip/hip_bf16.h>
#include <stdint.h>

// Problem: out[N,OUT] = x[N,IN] @ weight[OUT,IN]^T + bias[OUT]
// N=4096, IN(K)=2048, OUT=2048, all fp32 in/out.
#define NROWS 4096
#define KDIM  2048
#define ODIM  2048
#define NT    (KDIM / 32)   // 64 K-steps

typedef __bf16 bf16x8 __attribute__((ext_vector_type(8)));
typedef float  f32x4  __attribute__((ext_vector_type(4)));
typedef unsigned short u16;
typedef unsigned int   u32;

__device__ __forceinline__ u16 f32_to_bf16_rne(float f) {
  u32 u = __builtin_bit_cast(u32, f);
  u += 0x7FFFu + ((u >> 16) & 1u);   // round-to-nearest-even (inputs are finite normals)
  return (u16)(u >> 16);
}

// fused fp32 -> bf16 conversion for BOTH x and w in one launch (grid-stride)
__global__ void cvt_both_f32_to_bf16(const float* __restrict__ x,
                                     const float* __restrict__ w,
                                     u16* __restrict__ xb, u16* __restrict__ wb,
                                     int n4x, int n4w) {
  int i = blockIdx.x * blockDim.x + threadIdx.x;
  const int stride = gridDim.x * blockDim.x;
  const int total = n4x + n4w;
  for (; i < total; i += stride) {
    const float4* in;
    ushort4* out;
    int j;
    if (i < n4x) { in = (const float4*)x; out = (ushort4*)xb; j = i; }
    else         { in = (const float4*)w; out = (ushort4*)wb; j = i - n4x; }
    float4 v = in[j];
    ushort4 o;
    o.x = f32_to_bf16_rne(v.x);
    o.y = f32_to_bf16_rne(v.y);
    o.z = f32_to_bf16_rne(v.z);
    o.w = f32_to_bf16_rne(v.w);
    out[j] = o;
  }
}

// async global->LDS, 16B per lane; LDS dest is wave-uniform base (+lane*16 in HW)
__device__ __forceinline__ void async16(const u16* g, const u16* l) {
  __builtin_amdgcn_global_load_lds((const __attribute__((address_space(1))) u32*)g,
                                   (__attribute__((address_space(3))) u32*)l,
                                   16, 0, 0);
}

// 2-phase double-buffered bf16 GEMM-BT (T3-minimum recipe):
// 128x128 tile, BK=32, 256 threads = 4 waves (2x2), each wave 64x64 (4x4 frags 16x16x32).
// Per iter: STAGE(next tile -> other buffer) BEFORE ds_read+MFMA(current), ONE barrier.
__global__ void __launch_bounds__(256)
gemm_bt_bf16(const u16* __restrict__ A, const u16* __restrict__ B,
             const float* __restrict__ bias, float* __restrict__ C) {
  // [2 buffers][128 rows][32 k] u16
  __shared__ __align__(16) u16 As[2 * 128 * 32];
  __shared__ __align__(16) u16 Bs[2 * 128 * 32];

  const int t    = threadIdx.x;
  const int lane = t & 63;
  const int wave = t >> 6;
  const int wrow = wave >> 1;   // 0..1
  const int wcol = wave & 1;    // 0..1
  const int fr   = lane & 15;   // A-row / B-col / C-col within fragment
  const int fq   = lane >> 4;   // 0..3: k-chunk for A/B, row-group for C

  const int bx   = blockIdx.x;
  const int brow = (bx >> 4) * 128;  // 32 row-blocks
  const int bcol = (bx & 15) * 128;  // 16 col-blocks

  // staging source addresses: 256 threads cover a 64-row half-tile (16B/lane)
  const int srow = t >> 2;          // 0..63
  const int scol = (t & 3) * 8;     // k-offset, 8 bf16 = 16B
  const u16* pA0 = A + (size_t)(brow + srow)      * KDIM + scol;
  const u16* pA1 = A + (size_t)(brow + 64 + srow) * KDIM + scol;
  const u16* pB0 = B + (size_t)(bcol + srow)      * KDIM + scol;
  const u16* pB1 = B + (size_t)(bcol + 64 + srow) * KDIM + scol;

  f32x4 acc[4][4] = {};

  // fragment read offsets within a buffer (elements): row*32 + k_chunk*8
  const int aoff = (wrow * 64 + fr) * 32 + fq * 8;  // + m*16*32
  const int boff = (wcol * 64 + fr) * 32 + fq * 8;  // + n*16*32

#define STAGE(buf)                                                   \
  do {                                                               \
    u16* la = As + (buf) * 4096 + wave * 512;                        \
    u16* lb = Bs + (buf) * 4096 + wave * 512;                        \
    async16(pA0, la);                                                \
    async16(pA1, la + 2048);                                         \
    async16(pB0, lb);                                                \
    async16(pB1, lb + 2048);                                         \
    pA0 += 32; pA1 += 32; pB0 += 32; pB1 += 32;                      \
  } while (0)

#define COMPUTE(buf)                                                 \
  do {                                                               \
    const u16* ab = As + (buf) * 4096 + aoff;                        \
    const u16* bb = Bs + (buf) * 4096 + boff;                        \
    bf16x8 af[4], bf[4];                                             \
    _Pragma("unroll")                                                \
    for (int m = 0; m < 4; ++m)                                      \
      af[m] = *reinterpret_cast<const bf16x8*>(ab + m * 512);        \
    _Pragma("unroll")                                                \
    for (int n = 0; n < 4; ++n)                                      \
      bf[n] = *reinterpret_cast<const bf16x8*>(bb + n * 512);        \
    _Pragma("unroll")                                                \
    for (int m = 0; m < 4; ++m)                                      \
      _Pragma("unroll")                                              \
      for (int n = 0; n < 4; ++n)                                    \
        acc[m][n] = __builtin_amdgcn_mfma_f32_16x16x32_bf16(         \
            af[m], bf[n], acc[m][n], 0, 0, 0);                       \
  } while (0)

  // prologue: stage tile 0 into buffer 0
  STAGE(0);
  __syncthreads();   // compiler drains vmcnt(0) before barrier -> buf0 ready

  int cur = 0;
  for (int kt = 0; kt < NT - 1; ++kt) {
    STAGE(cur ^ 1);  // issue next tile's loads FIRST (overlap with MFMA below)
    COMPUTE(cur);
    __syncthreads(); // one barrier per K-step: drains vmcnt + lgkm, flips safely
    cur ^= 1;
  }
  COMPUTE(cur);      // last tile, no prefetch

#undef STAGE
#undef COMPUTE

  // ---- epilogue: C/D layout col=lane&15, row=(lane>>4)*4+reg ----
  float bv[4];
#pragma unroll
  for (int n = 0; n < 4; ++n)
    bv[n] = bias[bcol + wcol * 64 + n * 16 + fr];
#pragma unroll
  for (int m = 0; m < 4; ++m) {
    const int row0 = brow + wrow * 64 + m * 16 + fq * 4;
#pragma unroll
    for (int n = 0; n < 4; ++n) {
      const int col = bcol + wcol * 64 + n * 16 + fr;
      float* o = C + (size_t)row0 * ODIM + col;
#pragma unroll
      for (int j = 0; j < 4; ++j)
        o[(size_t)j * ODIM] = acc[m][n][j] + bv[n];
    }
  }
}

// correctness-only fallback if ws is too small (fp32, 16x16 LDS tiles)
__global__ void fallback_gemm(const float* __restrict__ x, const float* __restrict__ w,
                              const float* __restrict__ bias, float* __restrict__ out) {
  __shared__ float xs[16][17];
  __shared__ float wsm[16][17];
  const int tx = threadIdx.x & 15, ty = threadIdx.x >> 4;
  const int row = blockIdx.y * 16 + ty;
  const int colb = blockIdx.x * 16;
  float acc = 0.f;
  for (int k0 = 0; k0 < KDIM; k0 += 16) {
    xs[ty][tx]  = x[(size_t)row * KDIM + k0 + tx];
    wsm[ty][tx] = w[(size_t)(colb + ty) * KDIM + k0 + tx];
    __syncthreads();
#pragma unroll
    for (int kk = 0; kk < 16; ++kk)
      acc += xs[ty][kk] * wsm[tx][kk];
    __syncthreads();
  }
  out[(size_t)row * ODIM + colb + tx] = acc + bias[colb + tx];
}

extern "C" void kernel_launch(void* const* d_in, const int* in_sizes, int n_in,
                              void* d_out, int out_size, void* d_ws, size_t ws_size,
                              hipStream_t stream) {
  const float* x    = (const float*)d_in[0];
  const float* w    = (const float*)d_in[1];
  const float* bias = (const float*)d_in[2];
  float* out = (float*)d_out;

  const size_t needA = (size_t)NROWS * KDIM * sizeof(u16); // 16 MiB
  const size_t needB = (size_t)ODIM  * KDIM * sizeof(u16); //  8 MiB
  if (ws_size < needA + needB) {
    dim3 grid(ODIM / 16, NROWS / 16);
    fallback_gemm<<<grid, 256, 0, stream>>>(x, w, bias, out);
    return;
  }

  u16* xb = (u16*)d_ws;
  u16* wb = xb + (size_t)NROWS * KDIM;

  const int n4x = NROWS * KDIM / 4;  // 2M float4
  const int n4w = ODIM * KDIM / 4;   // 1M float4
  cvt_both_f32_to_bf16<<<2048, 256, 0, stream>>>(x, w, xb, wb, n4x, n4w);
  gemm_bt_bf16<<<512, 256, 0, stream>>>(xb, wb, bias, out);
}

// Round 3
// 55.851 us; speedup vs baseline: 1.3008x; 1.3008x over previous
//
#include <hip/hip_runtime.h>
#include <hip/hip_bf16.h>
#include <stdint.h>

// Problem: out[N,OUT] = x[N,IN] @ weight[OUT,IN]^T + bias[OUT]
// N=4096, IN(K)=2048, OUT=2048, all fp32 in/out.
#define NROWS 4096
#define KDIM  2048
#define ODIM  2048
#define BK    128
#define NT    (KDIM / BK)   // 16 K-steps

typedef __bf16 bf16x8 __attribute__((ext_vector_type(8)));
typedef float  f32x4  __attribute__((ext_vector_type(4)));
typedef unsigned short u16;
typedef unsigned int   u32;

__device__ __forceinline__ u16 f32_to_bf16_rne(float f) {
  u32 u = __builtin_bit_cast(u32, f);
  u += 0x7FFFu + ((u >> 16) & 1u);   // round-to-nearest-even (inputs finite)
  return (u16)(u >> 16);
}

// fused fp32 -> bf16 conversion for BOTH x and w in one launch (grid-stride)
__global__ void cvt_both_f32_to_bf16(const float* __restrict__ x,
                                     const float* __restrict__ w,
                                     u16* __restrict__ xb, u16* __restrict__ wb,
                                     int n4x, int n4w) {
  int i = blockIdx.x * blockDim.x + threadIdx.x;
  const int stride = gridDim.x * blockDim.x;
  const int total = n4x + n4w;
  for (; i < total; i += stride) {
    const float4* in;
    ushort4* out;
    int j;
    if (i < n4x) { in = (const float4*)x; out = (ushort4*)xb; j = i; }
    else         { in = (const float4*)w; out = (ushort4*)wb; j = i - n4x; }
    float4 v = in[j];
    ushort4 o;
    o.x = f32_to_bf16_rne(v.x);
    o.y = f32_to_bf16_rne(v.y);
    o.z = f32_to_bf16_rne(v.z);
    o.w = f32_to_bf16_rne(v.w);
    out[j] = o;
  }
}

// async global->LDS, 16B/lane; LDS dest is wave-uniform base (+lane*16 in HW)
__device__ __forceinline__ void async16(const u16* g, const u16* l) {
  __builtin_amdgcn_global_load_lds((const __attribute__((address_space(1))) u32*)g,
                                   (__attribute__((address_space(3))) u32*)l,
                                   16, 0, 0);
}

// Two-barrier bf16 GEMM-BT (R1-proven skeleton), BK=128, swizzled LDS.
// 128x128 tile, 256 threads = 4 waves (2x2), each wave 64x64 (4x4 frags 16x16x32).
// LDS layout: LDS[row][c ^ ((row&7)*8)] = global[row][c]  (u16 units).
// Achieved by: linear global_load_lds dest + inverse-swizzled GLOBAL src col
// (rule 21), same XOR on ds_read side.
__global__ void __launch_bounds__(256)
gemm_bt_bf16(const u16* __restrict__ A, const u16* __restrict__ B,
             const float* __restrict__ bias, float* __restrict__ C) {
  __shared__ __align__(16) u16 As[128 * BK];   // 32 KB
  __shared__ __align__(16) u16 Bs[128 * BK];   // 32 KB

  const int t    = threadIdx.x;
  const int lane = t & 63;
  const int wave = t >> 6;
  const int wrow = wave >> 1;   // 0..1
  const int wcol = wave & 1;    // 0..1
  const int fr   = lane & 15;   // A-row / B-col / C-col within fragment
  const int fq   = lane >> 4;   // 0..3: k-chunk for A/B, row-group for C

  // T1 XCD-aware swizzle: 512 blocks, 512%8==0 -> simple bijective form.
  const int bid  = blockIdx.x;
  const int swz  = (bid & 7) * 64 + (bid >> 3);
  const int brow = (swz >> 4) * 128;  // 32 row-blocks
  const int bcol = (swz & 15) * 128;  // 16 col-blocks

  // ---- staging: 8 groups of 16 rows per operand; lane covers 16B ----
  // thread t covers LDS row (t>>4) of its group, u16 col (t&15)*8 (linear dest).
  // Inverse-swizzled global col so LDS ends up swizzled:
  const int srow = t >> 4;                                  // 0..15
  const int scol = ((t & 15) ^ ((t >> 4) & 7)) * 8;         // u16 units
  const u16* pA = A + (size_t)(brow + srow) * KDIM + scol;
  const u16* pB = B + (size_t)(bcol + srow) * KDIM + scol;
  u16* lA = As + wave * 512;   // + g*2048
  u16* lB = Bs + wave * 512;

  f32x4 acc[4][4] = {};

  // fragment read bases (u16): row*BK, XOR term (R&7)*8 == (fr&7)*8
  const int xr    = (fr & 7) * 8;
  const int abase = (wrow * 64 + fr) * BK;  // + m*16*BK
  const int bbase = (wcol * 64 + fr) * BK;  // + n*16*BK

  for (int kt = 0; kt < NT; ++kt) {
    __syncthreads();                 // prior COMPUTE's ds_reads done
#pragma unroll
    for (int g = 0; g < 8; ++g) {
      async16(pA + (size_t)g * 16 * KDIM, lA + g * 2048);
      async16(pB + (size_t)g * 16 * KDIM, lB + g * 2048);
    }
    pA += BK; pB += BK;
    __syncthreads();                 // drains vmcnt(0): tile ready

#pragma unroll
    for (int kk = 0; kk < 4; ++kk) {
      const int ck = (kk * 32 + fq * 8) ^ xr;   // swizzled col (u16)
      bf16x8 af[4], bf[4];
#pragma unroll
      for (int m = 0; m < 4; ++m)
        af[m] = *reinterpret_cast<const bf16x8*>(As + abase + m * 16 * BK + ck);
#pragma unroll
      for (int n = 0; n < 4; ++n)
        bf[n] = *reinterpret_cast<const bf16x8*>(Bs + bbase + n * 16 * BK + ck);
#pragma unroll
      for (int m = 0; m < 4; ++m)
#pragma unroll
        for (int n = 0; n < 4; ++n)
          acc[m][n] = __builtin_amdgcn_mfma_f32_16x16x32_bf16(
              af[m], bf[n], acc[m][n], 0, 0, 0);
    }
  }

  // ---- epilogue: C/D layout col=lane&15, row=(lane>>4)*4+reg ----
  float bv[4];
#pragma unroll
  for (int n = 0; n < 4; ++n)
    bv[n] = bias[bcol + wcol * 64 + n * 16 + fr];
#pragma unroll
  for (int m = 0; m < 4; ++m) {
    const int row0 = brow + wrow * 64 + m * 16 + fq * 4;
#pragma unroll
    for (int n = 0; n < 4; ++n) {
      const int col = bcol + wcol * 64 + n * 16 + fr;
      float* o = C + (size_t)row0 * ODIM + col;
#pragma unroll
      for (int j = 0; j < 4; ++j)
        o[(size_t)j * ODIM] = acc[m][n][j] + bv[n];
    }
  }
}

// correctness-only fallback if ws is too small (fp32, 16x16 LDS tiles)
__global__ void fallback_gemm(const float* __restrict__ x, const float* __restrict__ w,
                              const float* __restrict__ bias, float* __restrict__ out) {
  __shared__ float xs[16][17];
  __shared__ float wsm[16][17];
  const int tx = threadIdx.x & 15, ty = threadIdx.x >> 4;
  const int row = blockIdx.y * 16 + ty;
  const int colb = blockIdx.x * 16;
  float acc = 0.f;
  for (int k0 = 0; k0 < KDIM; k0 += 16) {
    xs[ty][tx]  = x[(size_t)row * KDIM + k0 + tx];
    wsm[ty][tx] = w[(size_t)(colb + ty) * KDIM + k0 + tx];
    __syncthreads();
#pragma unroll
    for (int kk = 0; kk < 16; ++kk)
      acc += xs[ty][kk] * wsm[tx][kk];
    __syncthreads();
  }
  out[(size_t)row * ODIM + colb + tx] = acc + bias[colb + tx];
}

extern "C" void kernel_launch(void* const* d_in, const int* in_sizes, int n_in,
                              void* d_out, int out_size, void* d_ws, size_t ws_size,
                              hipStream_t stream) {
  const float* x    = (const float*)d_in[0];
  const float* w    = (const float*)d_in[1];
  const float* bias = (const float*)d_in[2];
  float* out = (float*)d_out;

  const size_t needA = (size_t)NROWS * KDIM * sizeof(u16); // 16 MiB
  const size_t needB = (size_t)ODIM  * KDIM * sizeof(u16); //  8 MiB
  if (ws_size < needA + needB) {
    dim3 grid(ODIM / 16, NROWS / 16);
    fallback_gemm<<<grid, 256, 0, stream>>>(x, w, bias, out);
    return;
  }

  u16* xb = (u16*)d_ws;
  u16* wb = xb + (size_t)NROWS * KDIM;

  const int n4x = NROWS * KDIM / 4;  // 2M float4
  const int n4w = ODIM * KDIM / 4;   // 1M float4
  cvt_both_f32_to_bf16<<<2048, 256, 0, stream>>>(x, w, xb, wb, n4x, n4w);
  gemm_bt_bf16<<<512, 256, 0, stream>>>(xb, wb, bias, out);
}